// Round 3
// baseline (195.059 us; speedup 1.0000x reference)
//
#include <hip/hip_runtime.h>

#define EMB 2048
#define NC 4
#define NROWS 16384
#define SCALE_S 16.0f

// Block = 256 threads = 4 waves. Each wave processes RG=4 rows CONCURRENTLY
// (one group), NG=2 groups sequentially -> 32 rows/block, grid = 512.
// Key change vs v2: the per-lane W fragment (sW[c*512 + j*64 + lane]) is
// row-invariant, so processing 4 rows per j-iteration reuses each LDS read
// 4x in registers -> LDS W-read traffic cut 4x (10.2 -> 2.6 us per CU).
// Next group's 32 global loads issue while the 120-op shuffle-reduce of the
// current group runs (x[][] is dead after the j-loop) -> VMEM hides under DS.
// ~180 VGPR -> 2 waves/SIMD (declared), 2 blocks/CU, 64 KB LDS/CU.
#define RG 4
#define NG 2
#define WAVES_PER_BLOCK 4
#define ROWS_PER_BLOCK (RG * NG * WAVES_PER_BLOCK)   // 32

__global__ __launch_bounds__(256, 2) void binary_head_kernel(
    const float* __restrict__ fea,
    const float* __restrict__ W,
    const float* __restrict__ bias,
    float* __restrict__ out)
{
    // W as float4: 4 classes x 512 float4 = 32 KB
    __shared__ float4 sW[NC * (EMB / 4)];

    const int tid = threadIdx.x;

    // Stage W -> LDS: 2048 float4 by 256 threads = 8 each, coalesced.
    const float4* W4 = (const float4*)W;
#pragma unroll
    for (int i = 0; i < 8; ++i) {
        sW[i * 256 + tid] = W4[i * 256 + tid];
    }

    const int wave = tid >> 6;
    const int lane = tid & 63;

    // Preload bias once (only lanes 0..3 use it).
    const float bval = bias[lane & (NC - 1)];

    const float4* fea4 = (const float4*)fea;
    const int waveRowBase = blockIdx.x * ROWS_PER_BLOCK + wave * (RG * NG);

    // Group-0 loads issued before the barrier.
    float4 x[RG][8];
#pragma unroll
    for (int r = 0; r < RG; ++r) {
        const float4* frow = fea4 + (size_t)(waveRowBase + r) * (EMB / 4);
#pragma unroll
        for (int j = 0; j < 8; ++j) {
            x[r][j] = frow[j * 64 + lane];
        }
    }

    __syncthreads();   // W visible to all waves

#pragma unroll
    for (int g = 0; g < NG; ++g) {
        float ss[RG] = {0.0f, 0.0f, 0.0f, 0.0f};
        float d[RG][NC] = {};

#pragma unroll
        for (int j = 0; j < 8; ++j) {
            const int col = j * 64 + lane;
            // One LDS read per class per j, reused across RG rows.
            const float4 w0 = sW[0 * 512 + col];
            const float4 w1 = sW[1 * 512 + col];
            const float4 w2 = sW[2 * 512 + col];
            const float4 w3 = sW[3 * 512 + col];
#pragma unroll
            for (int r = 0; r < RG; ++r) {
                const float4 v = x[r][j];
                ss[r]   += v.x * v.x  + v.y * v.y  + v.z * v.z  + v.w * v.w;
                d[r][0] += v.x * w0.x + v.y * w0.y + v.z * w0.z + v.w * w0.w;
                d[r][1] += v.x * w1.x + v.y * w1.y + v.z * w1.z + v.w * w1.w;
                d[r][2] += v.x * w2.x + v.y * w2.y + v.z * w2.z + v.w * w2.w;
                d[r][3] += v.x * w3.x + v.y * w3.y + v.z * w3.z + v.w * w3.w;
            }
        }

        // x is dead: issue next group's loads so they fly under the reduction.
        if (g + 1 < NG) {
            const int nb = waveRowBase + (g + 1) * RG;
#pragma unroll
            for (int r = 0; r < RG; ++r) {
                const float4* frow = fea4 + (size_t)(nb + r) * (EMB / 4);
#pragma unroll
                for (int j = 0; j < 8; ++j) {
                    x[r][j] = frow[j * 64 + lane];
                }
            }
        }

        // 64-lane butterfly on 20 independent chains (4 rows x {ss,d0..d3}).
#pragma unroll
        for (int m = 1; m < 64; m <<= 1) {
#pragma unroll
            for (int r = 0; r < RG; ++r) {
                ss[r]   += __shfl_xor(ss[r],   m, 64);
                d[r][0] += __shfl_xor(d[r][0], m, 64);
                d[r][1] += __shfl_xor(d[r][1], m, 64);
                d[r][2] += __shfl_xor(d[r][2], m, 64);
                d[r][3] += __shfl_xor(d[r][3], m, 64);
            }
        }

        const int row0 = waveRowBase + g * RG;
        if (lane < NC) {
#pragma unroll
            for (int r = 0; r < RG; ++r) {
                const float dv = (lane == 0) ? d[r][0]
                               : (lane == 1) ? d[r][1]
                               : (lane == 2) ? d[r][2]
                               :               d[r][3];
                out[(row0 + r) * NC + lane] = (dv * rsqrtf(ss[r]) + bval) * SCALE_S;
            }
        }
    }
}

extern "C" void kernel_launch(void* const* d_in, const int* in_sizes, int n_in,
                              void* d_out, int out_size, void* d_ws, size_t ws_size,
                              hipStream_t stream) {
    const float* fea  = (const float*)d_in[0];
    const float* W    = (const float*)d_in[1];
    const float* bias = (const float*)d_in[2];
    float* out = (float*)d_out;

    const int grid = NROWS / ROWS_PER_BLOCK;  // 16384 / 32 = 512 -> 2 blocks/CU
    binary_head_kernel<<<grid, 256, 0, stream>>>(fea, W, bias, out);
}

// Round 4
// 189.570 us; speedup vs baseline: 1.0290x; 1.0290x over previous
//
#include <hip/hip_runtime.h>

#define EMB 2048
#define NC 4
#define NROWS 16384
#define SCALE_S 16.0f

// REVERT to best-measured variant (189.8 us): one wave per row, 4 waves/block,
// software-pipelined row loop. Three structurally different kernels (serial,
// pipelined, 4-row register-tiled) all measured 190+-5 us total; the timed
// region is dominated by harness workspace re-poison (2x77.6 us fills at 86%
// HBM peak). Kernel compulsory traffic = 134.5 MB -> ~19.5 us floor at the
// fill-demonstrated 6.9 TB/s; kernel is at that floor within noise.
#define ROWS_PER_WAVE 4
#define WAVES_PER_BLOCK 4
#define ROWS_PER_BLOCK (ROWS_PER_WAVE * WAVES_PER_BLOCK)   // 16

__global__ __launch_bounds__(256) void binary_head_kernel(
    const float* __restrict__ fea,
    const float* __restrict__ W,
    const float* __restrict__ bias,
    float* __restrict__ out)
{
    // W as float4: 4 classes x 512 float4 = 2048 float4 = 32 KB
    __shared__ float4 sW[NC * (EMB / 4)];

    const int tid = threadIdx.x;

    // Stage W -> LDS: 2048 float4 by 256 threads = 8 each, coalesced.
    const float4* W4 = (const float4*)W;
#pragma unroll
    for (int i = 0; i < 8; ++i) {
        sW[i * 256 + tid] = W4[i * 256 + tid];
    }

    const int wave = tid >> 6;
    const int lane = tid & 63;

    // Preload bias once (all lanes load b[lane&3]; only lanes 0..3 use it).
    const float bval = bias[lane & (NC - 1)];

    const float4* fea4 = (const float4*)fea;
    const int rowBase = blockIdx.x * ROWS_PER_BLOCK + wave * ROWS_PER_WAVE;

    // Prologue: issue row 0's loads BEFORE the barrier so they overlap
    // the wait on W staging.
    float4 x[8], xn[8];
    {
        const float4* frow = fea4 + (size_t)rowBase * (EMB / 4);
#pragma unroll
        for (int j = 0; j < 8; ++j) {
            x[j] = frow[j * 64 + lane];
        }
    }

    __syncthreads();   // W visible to all waves

#pragma unroll
    for (int r = 0; r < ROWS_PER_WAVE; ++r) {
        // Prefetch next row while computing/reducing this one.
        if (r + 1 < ROWS_PER_WAVE) {
            const float4* fnext = fea4 + (size_t)(rowBase + r + 1) * (EMB / 4);
#pragma unroll
            for (int j = 0; j < 8; ++j) {
                xn[j] = fnext[j * 64 + lane];
            }
        }

        float ss = 0.0f, d0 = 0.0f, d1 = 0.0f, d2 = 0.0f, d3 = 0.0f;
#pragma unroll
        for (int j = 0; j < 8; ++j) {
            const float4 v = x[j];
            const int col = j * 64 + lane;

            ss += v.x * v.x + v.y * v.y + v.z * v.z + v.w * v.w;

            const float4 w0 = sW[0 * 512 + col];
            d0 += v.x * w0.x + v.y * w0.y + v.z * w0.z + v.w * w0.w;
            const float4 w1 = sW[1 * 512 + col];
            d1 += v.x * w1.x + v.y * w1.y + v.z * w1.z + v.w * w1.w;
            const float4 w2 = sW[2 * 512 + col];
            d2 += v.x * w2.x + v.y * w2.y + v.z * w2.z + v.w * w2.w;
            const float4 w3 = sW[3 * 512 + col];
            d3 += v.x * w3.x + v.y * w3.y + v.z * w3.z + v.w * w3.w;
        }

        // Wave-wide butterfly reduction (64 lanes) for all 5 partials.
#pragma unroll
        for (int m = 1; m < 64; m <<= 1) {
            ss += __shfl_xor(ss, m, 64);
            d0 += __shfl_xor(d0, m, 64);
            d1 += __shfl_xor(d1, m, 64);
            d2 += __shfl_xor(d2, m, 64);
            d3 += __shfl_xor(d3, m, 64);
        }

        const int row = rowBase + r;
        if (lane < NC) {
            const float d = (lane == 0) ? d0 : (lane == 1) ? d1 : (lane == 2) ? d2 : d3;
            const float inv = rsqrtf(ss);
            out[row * NC + lane] = (d * inv + bval) * SCALE_S;
        }

        // Rotate pipeline registers (dead on last iteration; compiler elides).
        if (r + 1 < ROWS_PER_WAVE) {
#pragma unroll
            for (int j = 0; j < 8; ++j) {
                x[j] = xn[j];
            }
        }
    }
}

extern "C" void kernel_launch(void* const* d_in, const int* in_sizes, int n_in,
                              void* d_out, int out_size, void* d_ws, size_t ws_size,
                              hipStream_t stream) {
    const float* fea  = (const float*)d_in[0];
    const float* W    = (const float*)d_in[1];
    const float* bias = (const float*)d_in[2];
    float* out = (float*)d_out;

    const int grid = NROWS / ROWS_PER_BLOCK;  // 16384 / 16 = 1024
    binary_head_kernel<<<grid, 256, 0, stream>>>(fea, W, bias, out);
}